// Round 1
// baseline (258.479 us; speedup 1.0000x reference)
//
#include <hip/hip_runtime.h>

#define BATCH 64
#define SEQ   128
#define NLAB  32
#define NEGF  -3.0e38f
#define PA    132

// ---------------------------------------------------------------------------
// Kernel 1 (v4): pot + gold partials + inline len. (unchanged from R9)
// ---------------------------------------------------------------------------
__global__ __launch_bounds__(256) void pot_gold_kernel(
    const float* __restrict__ logits, const int* __restrict__ labels,
    float* __restrict__ pot, float* __restrict__ gpart)
{
    const int tid = threadIdx.x;
    const int wave = tid >> 6, lane = tid & 63;
    __shared__ __align__(16) float LP[4 * 16 * 36];   // 9216 B
    __shared__ float gred[4];
    __shared__ int s_len;
    float* W = LP + wave * (16 * 36);

    const int block_cell0 = blockIdx.x * 256;
    const int b = block_cell0 >> 14;
    const bool has_row0 = (blockIdx.x & 63) == 0;

    if (has_row0 && tid < 64) {
        const size_t base = (size_t)b << 14;
        int cnt = (labels[base + tid] != -100) + (labels[base + 64 + tid] != -100);
        #pragma unroll
        for (int d = 32; d; d >>= 1) cnt += __shfl_down(cnt, d, 64);
        if (tid == 0) s_len = cnt;
    }
    __syncthreads();
    const int len = has_row0 ? s_len : -1;

    float gacc = 0.0f;
    const int wave_cell0 = block_cell0 + wave * 64;

    #pragma unroll
    for (int chunk = 0; chunk < 4; ++chunk) {
        const int c0 = wave_cell0 + chunk * 16;
        const float4* src = reinterpret_cast<const float4*>(logits) + ((size_t)c0 << 3);
        const float4 f0 = src[lane];
        const float4 f1 = src[lane + 64];
        const int lv = (lane < 16) ? labels[c0 + lane] : 0;

        {
            const int cA = lane >> 3, tA = lane & 7;
            *reinterpret_cast<float4*>(W + cA * 36 + tA * 4) = f0;
            const int q1 = lane + 64;
            const int cB = q1 >> 3, tB = q1 & 7;
            *reinterpret_cast<float4*>(W + cB * 36 + tB * 4) = f1;
        }
        const int c = lane >> 2, u = lane & 3;
        const float4 r0 = *reinterpret_cast<const float4*>(W + c * 36 + u * 8);
        const float4 r1 = *reinterpret_cast<const float4*>(W + c * 36 + u * 8 + 4);

        int lab = __shfl(lv, c, 64);
        if (lab < 0) lab = 0;
        const float l0 = __shfl(r0.x, c << 2, 64);

        const int cell = c0 + c;
        const int ci = (cell >> 7) & (SEQ - 1);
        const int cj = cell & (SEQ - 1);
        const bool special = (ci == 0) && (cj == len - 1);

        const float vv[8] = { r0.x, r0.y, r0.z, r0.w, r1.x, r1.y, r1.z, r1.w };
        float m = NEGF, g = 0.0f;
        #pragma unroll
        for (int e = 0; e < 8; ++e) {
            const int l = u * 8 + e;
            const float r = vv[e] - l0;
            const bool isg = (l == lab);
            g = isg ? r : g;
            float cand = r + (isg ? 0.0f : 1.0f);
            if (l == 0 && special) cand -= 1.0e9f;
            m = fmaxf(m, cand);
        }
        m = fmaxf(m, __shfl_xor(m, 1, 64));
        m = fmaxf(m, __shfl_xor(m, 2, 64));
        g += __shfl_xor(g, 1, 64);
        g += __shfl_xor(g, 2, 64);
        if (u == 0) {
            pot[cell] = m;
            gacc += g;
        }
    }

    #pragma unroll
    for (int d = 1; d < 64; d <<= 1) gacc += __shfl_xor(gacc, d, 64);
    if (lane == 0) gred[wave] = gacc;
    __syncthreads();
    if (tid == 0)
        gpart[blockIdx.x] = gred[0] + gred[1] + gred[2] + gred[3];
}

// ---------------------------------------------------------------------------
// Kernel 2 (v8): CHUNKED two-phase max-plus CKY. One block (512 thr) / batch.
//   A [i][k] pitch 132 : span starting at i, width k (holds pot until step k)
//   Bt[j][c] pitch 132 : c = N-1-width (k-contiguous at every step)
// Width chunks [W, W+16). For step w = W+d, k-terms split:
//   bulk  k in [d, W-1] : BOTH operands older than chunk -> computed ONCE per
//                         chunk (phase A) into registers md[16], all 512
//                         threads busy, zero barriers inside.
//   edge1 k in [0, d-1] : alo[] (registers, = A[i][0..15], fixed after chunk0)
//                         + fresh-B burst Bt[j][width W..w-1] (contig quads).
//   edge2 k in [W, w-1] : own av[] (registers, this chunk's values)
//                         + old-B burst Bt[j][width 0..d-1] (contig quads).
// Serial interval per step: <=8 broadcast b128 + ~2d fmax + 2 writes.
// Chunk 0 (w=1..15) = edge2-only steps. Bulk B-alignment S=(-d)&3 folded at
// compile time (d fully unrolled); no NEGF pads needed (bursts only use
// valid elements; bulk first-quad masked in registers).
// ---------------------------------------------------------------------------
__global__ __launch_bounds__(512, 1) void cky_kernel(
    const float* __restrict__ pot, const float* __restrict__ gpart,
    const int* __restrict__ labels, float* __restrict__ out)
{
    const int b = blockIdx.x;
    const int tid = threadIdx.x;
    const float* p = pot + (size_t)b * SEQ * SEQ;

    __shared__ __align__(16) float A[SEQ * PA];       // 67584 B
    __shared__ __align__(16) float Bt[SEQ * PA];      // 67584 B
    __shared__ int s_len;
    __shared__ float s_gold;

    if (tid < 64) {                                   // len[b]
        const size_t base = (size_t)b << 14;
        int cnt = (labels[base + tid] != -100) + (labels[base + 64 + tid] != -100);
        #pragma unroll
        for (int d = 32; d; d >>= 1) cnt += __shfl_down(cnt, d, 64);
        if (tid == 0) s_len = cnt;
    } else if (tid < 128) {                           // gold[b] from partials
        float g = gpart[b * 64 + (tid - 64)];
        #pragma unroll
        for (int d = 32; d; d >>= 1) g += __shfl_down(g, d, 64);
        if (tid == 64) s_gold = g;
    }

    {   // scatter pot into both tables (coalesced global float4 reads)
        const float4* p4 = reinterpret_cast<const float4*>(p);
        for (int qi = tid; qi < SEQ * SEQ / 4; qi += 512) {
            const int i = qi >> 5;
            const int j0 = (qi & 31) << 2;
            const float4 v = p4[qi];
            const float vv[4] = { v.x, v.y, v.z, v.w };
            #pragma unroll
            for (int c2 = 0; c2 < 4; ++c2) {
                const int j = j0 + c2;
                if (j >= i) {
                    A[i * PA + (j - i)] = vv[c2];
                    Bt[j * PA + (SEQ - 1 - (j - i))] = vv[c2];
                }
            }
        }
    }
    __syncthreads();

    const int i = tid >> 2, s = tid & 3;
    float alo[16], av[16], pv[16], md[16];

    // ---------------- chunk 0: w = 1..15 (edge2-only) ----------------
    #pragma unroll
    for (int t = 0; t < 4; ++t) {
        const float4 v = *reinterpret_cast<const float4*>(&A[i * PA + 4 * t]);
        pv[4*t] = v.x; pv[4*t+1] = v.y; pv[4*t+2] = v.z; pv[4*t+3] = v.w;
    }
    av[0] = pv[0];
    #pragma unroll
    for (int d = 1; d < 16; ++d) {
        const int j = i + d;
        if (j < SEQ) {
            float bo[16];
            const int NQ = (d + 3) >> 2;
            #pragma unroll
            for (int t = 0; t < NQ; ++t) {   // quad covers widths 4t..4t+3 (reversed)
                const float4 v = *reinterpret_cast<const float4*>(&Bt[j * PA + 124 - 4 * t]);
                bo[4*t] = v.w; bo[4*t+1] = v.z; bo[4*t+2] = v.y; bo[4*t+3] = v.x;
            }
            float val = NEGF;
            #pragma unroll
            for (int m = 0; m < d; ++m)
                val = fmaxf(val, av[d - 1 - m] + bo[m]);
            val += pv[d];
            av[d] = val;
            if (s == 0) {
                A[i * PA + d] = val;
                Bt[j * PA + (SEQ - 1 - d)] = val;
            }
        }
        __syncthreads();
    }
    #pragma unroll
    for (int k = 0; k < 16; ++k) alo[k] = av[k];

    // ---------------- chunks W = 16..112 ----------------
    for (int W = 16; W < SEQ; W += 16) {
        // pv = A[i][W..W+15] (pot values, stable until this chunk's writes)
        #pragma unroll
        for (int t = 0; t < 4; ++t) {
            const float4 v = *reinterpret_cast<const float4*>(&A[i * PA + W + 4 * t]);
            pv[4*t] = v.x; pv[4*t+1] = v.y; pv[4*t+2] = v.z; pv[4*t+3] = v.w;
        }
        #pragma unroll
        for (int d = 0; d < 16; ++d) md[d] = NEGF;

        // ---- phase A: bulk k in [d, W-1], all data pre-chunk ----
        {   // first quad (k0 = 4s <= 12): mask k >= d
            const int k0 = s << 2;
            const float4 a = *reinterpret_cast<const float4*>(&A[i * PA + k0]);
            const float aa[4] = { a.x, a.y, a.z, a.w };
            #pragma unroll
            for (int d = 0; d < 16; ++d) {
                const int j = i + W + d;
                if (j < SEQ) {
                    const float* bp = &Bt[j * PA + (SEQ - W - d) + k0];
                    float b0, b1, b2, b3;
                    if ((d & 3) == 0) {
                        const float4 v = *reinterpret_cast<const float4*>(bp);
                        b0 = v.x; b1 = v.y; b2 = v.z; b3 = v.w;
                    } else if ((d & 3) == 2) {
                        const float2 v0 = *reinterpret_cast<const float2*>(bp);
                        const float2 v1 = *reinterpret_cast<const float2*>(bp + 2);
                        b0 = v0.x; b1 = v0.y; b2 = v1.x; b3 = v1.y;
                    } else {
                        b0 = bp[0];
                        const float2 v = *reinterpret_cast<const float2*>(bp + 1);
                        b1 = v.x; b2 = v.y; b3 = bp[3];
                    }
                    const float a0 = (k0 + 0 >= d) ? aa[0] : NEGF;
                    const float a1 = (k0 + 1 >= d) ? aa[1] : NEGF;
                    const float a2 = (k0 + 2 >= d) ? aa[2] : NEGF;
                    const float a3 = (k0 + 3 >= d) ? aa[3] : NEGF;
                    md[d] = fmaxf(md[d], fmaxf(fmaxf(a0 + b0, a1 + b1),
                                               fmaxf(a2 + b2, a3 + b3)));
                }
            }
        }
        for (int q = s + 4; q < (W >> 2); q += 4) {   // k0 >= 16 > d: no masks
            const int k0 = q << 2;
            const float4 a = *reinterpret_cast<const float4*>(&A[i * PA + k0]);
            #pragma unroll
            for (int d = 0; d < 16; ++d) {
                const int j = i + W + d;
                if (j < SEQ) {
                    const float* bp = &Bt[j * PA + (SEQ - W - d) + k0];
                    float b0, b1, b2, b3;
                    if ((d & 3) == 0) {
                        const float4 v = *reinterpret_cast<const float4*>(bp);
                        b0 = v.x; b1 = v.y; b2 = v.z; b3 = v.w;
                    } else if ((d & 3) == 2) {
                        const float2 v0 = *reinterpret_cast<const float2*>(bp);
                        const float2 v1 = *reinterpret_cast<const float2*>(bp + 2);
                        b0 = v0.x; b1 = v0.y; b2 = v1.x; b3 = v1.y;
                    } else {
                        b0 = bp[0];
                        const float2 v = *reinterpret_cast<const float2*>(bp + 1);
                        b1 = v.x; b2 = v.y; b3 = bp[3];
                    }
                    md[d] = fmaxf(md[d], fmaxf(fmaxf(a.x + b0, a.y + b1),
                                               fmaxf(a.z + b2, a.w + b3)));
                }
            }
        }
        #pragma unroll
        for (int d = 0; d < 16; ++d) {    // 4-lane butterfly
            md[d] = fmaxf(md[d], __shfl_xor(md[d], 1, 4));
            md[d] = fmaxf(md[d], __shfl_xor(md[d], 2, 4));
        }

        // ---- phase B: 16 tiny serial steps ----
        #pragma unroll
        for (int d = 0; d < 16; ++d) {
            const int w = W + d;
            const int j = i + w;
            if (j < SEQ) {
                float val = md[d];
                if (d > 0) {
                    float bo[16], bf[16];
                    const int NQ = (d + 3) >> 2;
                    #pragma unroll
                    for (int t = 0; t < NQ; ++t) {
                        // old-B: widths 4t..4t+3 (reversed quad)
                        const float4 v = *reinterpret_cast<const float4*>(&Bt[j * PA + 124 - 4 * t]);
                        bo[4*t] = v.w; bo[4*t+1] = v.z; bo[4*t+2] = v.y; bo[4*t+3] = v.x;
                        // fresh-B: widths W+4t..W+4t+3 (reversed quad)
                        const float4 u = *reinterpret_cast<const float4*>(&Bt[j * PA + 124 - W - 4 * t]);
                        bf[4*t] = u.w; bf[4*t+1] = u.z; bf[4*t+2] = u.y; bf[4*t+3] = u.x;
                    }
                    #pragma unroll
                    for (int m = 0; m < d; ++m) {
                        val = fmaxf(val, av[d - 1 - m] + bo[m]);    // k in [W, w-1]
                        val = fmaxf(val, alo[d - 1 - m] + bf[m]);   // k in [0, d-1]
                    }
                }
                val += pv[d];
                av[d] = val;
                if (s == 0) {
                    A[i * PA + w] = val;
                    Bt[j * PA + (SEQ - 1 - w)] = val;
                }
            }
            __syncthreads();
        }
    }

    if (tid == 0) {
        const int len = s_len;
        const float pred = A[len - 1];        // A[0][len-1]
        const float margin = fmaxf(pred - s_gold, 0.0f);
        atomicAdd(out, margin * (1.0f / (float)BATCH));
    }
}

extern "C" void kernel_launch(void* const* d_in, const int* in_sizes, int n_in,
                              void* d_out, int out_size, void* d_ws, size_t ws_size,
                              hipStream_t stream) {
    const float* logits = (const float*)d_in[0];
    const int* labels = (const int*)d_in[1];
    float* out = (float*)d_out;

    float* pot = (float*)d_ws;                          // B*N*N floats = 4 MB
    float* gpart = pot + (size_t)BATCH * SEQ * SEQ;     // 4096 floats

    (void)hipMemsetAsync(out, 0, sizeof(float), stream);

    pot_gold_kernel<<<BATCH * SEQ * SEQ / 256, 256, 0, stream>>>(
        logits, labels, pot, gpart);
    cky_kernel<<<BATCH, 512, 0, stream>>>(pot, gpart, labels, out);
}

// Round 2
// 258.012 us; speedup vs baseline: 1.0018x; 1.0018x over previous
//
#include <hip/hip_runtime.h>

#define BATCH 64
#define SEQ   128
#define NLAB  32
#define NEGF  -3.0e38f
#define PA    132

// counted-waitcnt barrier: wait until <=K LDS ops outstanding, then s_barrier.
// DS ops retire in-order, so writes issued BEFORE the last K reads are complete.
__device__ __forceinline__ void bar_k(int K) {
    switch (K) {
    case 0: asm volatile("s_waitcnt lgkmcnt(0)" ::: "memory"); break;
    case 1: asm volatile("s_waitcnt lgkmcnt(1)" ::: "memory"); break;
    case 2: asm volatile("s_waitcnt lgkmcnt(2)" ::: "memory"); break;
    case 3: asm volatile("s_waitcnt lgkmcnt(3)" ::: "memory"); break;
    case 4: asm volatile("s_waitcnt lgkmcnt(4)" ::: "memory"); break;
    case 5: asm volatile("s_waitcnt lgkmcnt(5)" ::: "memory"); break;
    case 6: asm volatile("s_waitcnt lgkmcnt(6)" ::: "memory"); break;
    default: asm volatile("s_waitcnt lgkmcnt(7)" ::: "memory"); break;
    }
    __builtin_amdgcn_s_barrier();
}

// ---------------------------------------------------------------------------
// Kernel 1 (v5): pot + gold partials + inline len + out zeroing.
// ---------------------------------------------------------------------------
__global__ __launch_bounds__(256) void pot_gold_kernel(
    const float* __restrict__ logits, const int* __restrict__ labels,
    float* __restrict__ pot, float* __restrict__ gpart, float* __restrict__ out)
{
    const int tid = threadIdx.x;
    const int wave = tid >> 6, lane = tid & 63;
    __shared__ __align__(16) float LP[4 * 16 * 36];   // 9216 B
    __shared__ float gred[4];
    __shared__ int s_len;
    float* W = LP + wave * (16 * 36);

    const int block_cell0 = blockIdx.x * 256;
    const int b = block_cell0 >> 14;
    const bool has_row0 = (blockIdx.x & 63) == 0;

    if (blockIdx.x == 0 && tid == 0) out[0] = 0.0f;   // replaces hipMemsetAsync

    if (has_row0 && tid < 64) {
        const size_t base = (size_t)b << 14;
        int cnt = (labels[base + tid] != -100) + (labels[base + 64 + tid] != -100);
        #pragma unroll
        for (int d = 32; d; d >>= 1) cnt += __shfl_down(cnt, d, 64);
        if (tid == 0) s_len = cnt;
    }
    __syncthreads();
    const int len = has_row0 ? s_len : -1;

    float gacc = 0.0f;
    const int wave_cell0 = block_cell0 + wave * 64;

    #pragma unroll
    for (int chunk = 0; chunk < 4; ++chunk) {
        const int c0 = wave_cell0 + chunk * 16;
        const float4* src = reinterpret_cast<const float4*>(logits) + ((size_t)c0 << 3);
        const float4 f0 = src[lane];
        const float4 f1 = src[lane + 64];
        const int lv = (lane < 16) ? labels[c0 + lane] : 0;

        {
            const int cA = lane >> 3, tA = lane & 7;
            *reinterpret_cast<float4*>(W + cA * 36 + tA * 4) = f0;
            const int q1 = lane + 64;
            const int cB = q1 >> 3, tB = q1 & 7;
            *reinterpret_cast<float4*>(W + cB * 36 + tB * 4) = f1;
        }
        const int c = lane >> 2, u = lane & 3;
        const float4 r0 = *reinterpret_cast<const float4*>(W + c * 36 + u * 8);
        const float4 r1 = *reinterpret_cast<const float4*>(W + c * 36 + u * 8 + 4);

        int lab = __shfl(lv, c, 64);
        if (lab < 0) lab = 0;
        const float l0 = __shfl(r0.x, c << 2, 64);

        const int cell = c0 + c;
        const int ci = (cell >> 7) & (SEQ - 1);
        const int cj = cell & (SEQ - 1);
        const bool special = (ci == 0) && (cj == len - 1);

        const float vv[8] = { r0.x, r0.y, r0.z, r0.w, r1.x, r1.y, r1.z, r1.w };
        float m = NEGF, g = 0.0f;
        #pragma unroll
        for (int e = 0; e < 8; ++e) {
            const int l = u * 8 + e;
            const float r = vv[e] - l0;
            const bool isg = (l == lab);
            g = isg ? r : g;
            float cand = r + (isg ? 0.0f : 1.0f);
            if (l == 0 && special) cand -= 1.0e9f;
            m = fmaxf(m, cand);
        }
        m = fmaxf(m, __shfl_xor(m, 1, 64));
        m = fmaxf(m, __shfl_xor(m, 2, 64));
        g += __shfl_xor(g, 1, 64);
        g += __shfl_xor(g, 2, 64);
        if (u == 0) {
            pot[cell] = m;
            gacc += g;
        }
    }

    #pragma unroll
    for (int d = 1; d < 64; d <<= 1) gacc += __shfl_xor(gacc, d, 64);
    if (lane == 0) gred[wave] = gacc;
    __syncthreads();
    if (tid == 0)
        gpart[blockIdx.x] = gred[0] + gred[1] + gred[2] + gred[3];
}

// ---------------------------------------------------------------------------
// Kernel 2 (v9): chunked two-phase CKY with PIPELINED phase-B steps.
// Per step w = W+d only ONE Bt quad is fresh (contains width w-1). All bo
// quads (widths 0..15, chunk-0 data) and older bf quads are prefetched in
// the PREVIOUS step and kept in flight across the barrier via counted
// s_waitcnt lgkmcnt(K) (DS retires in-order; writes issued before the K
// prefetch reads are guaranteed drained). Max-reductions are log-depth
// trees with compile-time indices only.
// ---------------------------------------------------------------------------
__global__ __launch_bounds__(512, 1) void cky_kernel(
    const float* __restrict__ pot, const float* __restrict__ gpart,
    const int* __restrict__ labels, float* __restrict__ out)
{
    const int b = blockIdx.x;
    const int tid = threadIdx.x;
    const float* p = pot + (size_t)b * SEQ * SEQ;

    __shared__ __align__(16) float A[SEQ * PA];       // 67584 B
    __shared__ __align__(16) float Bt[SEQ * PA];      // 67584 B
    __shared__ int s_len;
    __shared__ float s_gold;

    if (tid < 64) {                                   // len[b]
        const size_t base = (size_t)b << 14;
        int cnt = (labels[base + tid] != -100) + (labels[base + 64 + tid] != -100);
        #pragma unroll
        for (int d = 32; d; d >>= 1) cnt += __shfl_down(cnt, d, 64);
        if (tid == 0) s_len = cnt;
    } else if (tid < 128) {                           // gold[b] from partials
        float g = gpart[b * 64 + (tid - 64)];
        #pragma unroll
        for (int d = 32; d; d >>= 1) g += __shfl_down(g, d, 64);
        if (tid == 64) s_gold = g;
    }

    {   // scatter pot into both tables; preload all 8 quads first (ILP)
        const float4* p4 = reinterpret_cast<const float4*>(p);
        float4 vb[8];
        #pragma unroll
        for (int t = 0; t < 8; ++t) vb[t] = p4[tid + 512 * t];
        #pragma unroll
        for (int t = 0; t < 8; ++t) {
            const int qi = tid + 512 * t;
            const int i0 = qi >> 5;
            const int j0 = (qi & 31) << 2;
            const float vv[4] = { vb[t].x, vb[t].y, vb[t].z, vb[t].w };
            #pragma unroll
            for (int c2 = 0; c2 < 4; ++c2) {
                const int j = j0 + c2;
                if (j >= i0) {
                    A[i0 * PA + (j - i0)] = vv[c2];
                    Bt[j * PA + (SEQ - 1 - (j - i0))] = vv[c2];
                }
            }
        }
    }
    __syncthreads();

    const int i = tid >> 2, s = tid & 3;
    float alo[16], av[16], pv[16], md[16];
    float bo_p[16], bf_p[12];

    // ---------------- chunk 0: w = 1..15 ----------------
    #pragma unroll
    for (int t = 0; t < 4; ++t) {
        const float4 v = *reinterpret_cast<const float4*>(&A[i * PA + 4 * t]);
        pv[4*t] = v.x; pv[4*t+1] = v.y; pv[4*t+2] = v.z; pv[4*t+3] = v.w;
    }
    av[0] = pv[0];
    #pragma unroll
    for (int d = 1; d < 16; ++d) {
        const int j = i + d;
        const int tf = (d - 1) >> 2;
        const int jr = (j < SEQ) ? j : SEQ - 1;
        float bff[4];
        {   // fresh quad: widths 4tf..4tf+3 (reversed)
            const float4 u = *reinterpret_cast<const float4*>(&Bt[jr * PA + 124 - 4 * tf]);
            bff[0] = u.w; bff[1] = u.z; bff[2] = u.y; bff[3] = u.x;
        }
        float e[16];
        #pragma unroll
        for (int m = 0; m < d; ++m)
            e[m] = av[d - 1 - m] + ((m < 4 * tf) ? bo_p[m] : bff[m - 4 * tf]);
        #pragma unroll
        for (int stp = 1; stp < 16; stp <<= 1) {
            #pragma unroll
            for (int m = 0; m + stp < d; m += 2 * stp)
                e[m] = fmaxf(e[m], e[m + stp]);
        }
        const float val = e[0] + pv[d];
        av[d] = val;
        if (j < SEQ && s == 0) {
            A[i * PA + d] = val;
            Bt[j * PA + (SEQ - 1 - d)] = val;
        }
        __builtin_amdgcn_sched_barrier(0);
        if (d < 15) {   // prefetch old quads for step d+1 (widths <= d-1: visible)
            int jp = j + 1; if (jp >= SEQ) jp = SEQ - 1;
            const int tfn = d >> 2;
            #pragma unroll
            for (int t = 0; t < 4; ++t) {
                if (t < tfn) {
                    const float4 v = *reinterpret_cast<const float4*>(&Bt[jp * PA + 124 - 4 * t]);
                    bo_p[4*t] = v.w; bo_p[4*t+1] = v.z; bo_p[4*t+2] = v.y; bo_p[4*t+3] = v.x;
                }
            }
            bar_k(tfn);
        } else {
            bar_k(0);
        }
    }
    #pragma unroll
    for (int k = 0; k < 16; ++k) alo[k] = av[k];

    // ---------------- chunks W = 16..112 ----------------
    for (int W = 16; W < SEQ; W += 16) {
        // pv = A[i][W..W+15] (pot values, stable until this chunk's writes)
        #pragma unroll
        for (int t = 0; t < 4; ++t) {
            const float4 v = *reinterpret_cast<const float4*>(&A[i * PA + W + 4 * t]);
            pv[4*t] = v.x; pv[4*t+1] = v.y; pv[4*t+2] = v.z; pv[4*t+3] = v.w;
        }
        #pragma unroll
        for (int d = 0; d < 16; ++d) md[d] = NEGF;

        // ---- phase A: bulk k in [d, W-1], all data pre-chunk ----
        {   // first quad (k0 = 4s <= 12): mask k >= d
            const int k0 = s << 2;
            const float4 a = *reinterpret_cast<const float4*>(&A[i * PA + k0]);
            const float aa[4] = { a.x, a.y, a.z, a.w };
            #pragma unroll
            for (int d = 0; d < 16; ++d) {
                const int j = i + W + d;
                if (j < SEQ) {
                    const float* bp = &Bt[j * PA + (SEQ - W - d) + k0];
                    float b0, b1, b2, b3;
                    if ((d & 3) == 0) {
                        const float4 v = *reinterpret_cast<const float4*>(bp);
                        b0 = v.x; b1 = v.y; b2 = v.z; b3 = v.w;
                    } else if ((d & 3) == 2) {
                        const float2 v0 = *reinterpret_cast<const float2*>(bp);
                        const float2 v1 = *reinterpret_cast<const float2*>(bp + 2);
                        b0 = v0.x; b1 = v0.y; b2 = v1.x; b3 = v1.y;
                    } else {
                        b0 = bp[0];
                        const float2 v = *reinterpret_cast<const float2*>(bp + 1);
                        b1 = v.x; b2 = v.y; b3 = bp[3];
                    }
                    const float a0 = (k0 + 0 >= d) ? aa[0] : NEGF;
                    const float a1 = (k0 + 1 >= d) ? aa[1] : NEGF;
                    const float a2 = (k0 + 2 >= d) ? aa[2] : NEGF;
                    const float a3 = (k0 + 3 >= d) ? aa[3] : NEGF;
                    md[d] = fmaxf(md[d], fmaxf(fmaxf(a0 + b0, a1 + b1),
                                               fmaxf(a2 + b2, a3 + b3)));
                }
            }
        }
        for (int q = s + 4; q < (W >> 2); q += 4) {   // k0 >= 16 > d: no masks
            const int k0 = q << 2;
            const float4 a = *reinterpret_cast<const float4*>(&A[i * PA + k0]);
            #pragma unroll
            for (int d = 0; d < 16; ++d) {
                const int j = i + W + d;
                if (j < SEQ) {
                    const float* bp = &Bt[j * PA + (SEQ - W - d) + k0];
                    float b0, b1, b2, b3;
                    if ((d & 3) == 0) {
                        const float4 v = *reinterpret_cast<const float4*>(bp);
                        b0 = v.x; b1 = v.y; b2 = v.z; b3 = v.w;
                    } else if ((d & 3) == 2) {
                        const float2 v0 = *reinterpret_cast<const float2*>(bp);
                        const float2 v1 = *reinterpret_cast<const float2*>(bp + 2);
                        b0 = v0.x; b1 = v0.y; b2 = v1.x; b3 = v1.y;
                    } else {
                        b0 = bp[0];
                        const float2 v = *reinterpret_cast<const float2*>(bp + 1);
                        b1 = v.x; b2 = v.y; b3 = bp[3];
                    }
                    md[d] = fmaxf(md[d], fmaxf(fmaxf(a.x + b0, a.y + b1),
                                               fmaxf(a.z + b2, a.w + b3)));
                }
            }
        }
        #pragma unroll
        for (int d = 0; d < 16; ++d) {    // 4-lane butterfly
            md[d] = fmaxf(md[d], __shfl_xor(md[d], 1, 4));
            md[d] = fmaxf(md[d], __shfl_xor(md[d], 2, 4));
        }

        // ---- phase B: 16 pipelined serial steps ----
        {   // step d = 0: no edge terms; prefetch bo quad 0 for step 1
            const int j = i + W;
            const float val = md[0] + pv[0];
            av[0] = val;
            if (j < SEQ && s == 0) {
                A[i * PA + W] = val;
                Bt[j * PA + (SEQ - 1 - W)] = val;
            }
            __builtin_amdgcn_sched_barrier(0);
            int jp = j + 1; if (jp >= SEQ) jp = SEQ - 1;
            const float4 v = *reinterpret_cast<const float4*>(&Bt[jp * PA + 124]);
            bo_p[0] = v.w; bo_p[1] = v.z; bo_p[2] = v.y; bo_p[3] = v.x;
            bar_k(1);
        }
        #pragma unroll
        for (int d = 1; d < 16; ++d) {
            const int w = W + d;
            const int j = i + w;
            const int tf = (d - 1) >> 2;
            const int jr = (j < SEQ) ? j : SEQ - 1;
            float bff[4];
            {   // fresh bf quad: widths W+4tf..W+4tf+3 (reversed)
                const float4 u = *reinterpret_cast<const float4*>(&Bt[jr * PA + 124 - W - 4 * tf]);
                bff[0] = u.w; bff[1] = u.z; bff[2] = u.y; bff[3] = u.x;
            }
            float e[30];
            #pragma unroll
            for (int m = 0; m < d; ++m)             // edge2: own av + old-B (prefetched)
                e[m] = av[d - 1 - m] + bo_p[m];
            #pragma unroll
            for (int m = 0; m < d; ++m)             // edge1: alo + fresh-B (pf + 1 fresh quad)
                e[d + m] = alo[d - 1 - m] + ((m < 4 * tf) ? bf_p[m] : bff[m - 4 * tf]);
            #pragma unroll
            for (int stp = 1; stp < 32; stp <<= 1) {
                #pragma unroll
                for (int m = 0; m + stp < 2 * d; m += 2 * stp)
                    e[m] = fmaxf(e[m], e[m + stp]);
            }
            const float val = fmaxf(md[d], e[0]) + pv[d];
            av[d] = val;
            if (j < SEQ && s == 0) {
                A[i * PA + w] = val;
                Bt[j * PA + (SEQ - 1 - w)] = val;
            }
            __builtin_amdgcn_sched_barrier(0);
            if (d < 15) {   // prefetch for step d+1: all bo quads + old bf quads
                int jp = j + 1; if (jp >= SEQ) jp = SEQ - 1;
                const int NQn = (d + 4) >> 2;       // NQ(d+1)
                #pragma unroll
                for (int t = 0; t < 4; ++t) {
                    if (t < NQn) {
                        const float4 v = *reinterpret_cast<const float4*>(&Bt[jp * PA + 124 - 4 * t]);
                        bo_p[4*t] = v.w; bo_p[4*t+1] = v.z; bo_p[4*t+2] = v.y; bo_p[4*t+3] = v.x;
                    }
                }
                const int tfn = d >> 2;             // t_f(d+1)
                #pragma unroll
                for (int t = 0; t < 3; ++t) {
                    if (t < tfn) {
                        const float4 v = *reinterpret_cast<const float4*>(&Bt[jp * PA + 124 - W - 4 * t]);
                        bf_p[4*t] = v.w; bf_p[4*t+1] = v.z; bf_p[4*t+2] = v.y; bf_p[4*t+3] = v.x;
                    }
                }
                bar_k(NQn + tfn);
            } else {
                bar_k(0);
            }
        }
    }

    if (tid == 0) {
        const int len = s_len;
        const float pred = A[len - 1];        // A[0][len-1]
        const float margin = fmaxf(pred - s_gold, 0.0f);
        atomicAdd(out, margin * (1.0f / (float)BATCH));
    }
}

extern "C" void kernel_launch(void* const* d_in, const int* in_sizes, int n_in,
                              void* d_out, int out_size, void* d_ws, size_t ws_size,
                              hipStream_t stream) {
    const float* logits = (const float*)d_in[0];
    const int* labels = (const int*)d_in[1];
    float* out = (float*)d_out;

    float* pot = (float*)d_ws;                          // B*N*N floats = 4 MB
    float* gpart = pot + (size_t)BATCH * SEQ * SEQ;     // 4096 floats

    pot_gold_kernel<<<BATCH * SEQ * SEQ / 256, 256, 0, stream>>>(
        logits, labels, pot, gpart, out);
    cky_kernel<<<BATCH, 512, 0, stream>>>(pot, gpart, labels, out);
}

// Round 3
// 256.534 us; speedup vs baseline: 1.0076x; 1.0058x over previous
//
#include <hip/hip_runtime.h>

#define BATCH 64
#define SEQ   128
#define NLAB  32
#define NEGF  -3.0e38f
#define PA    132

// counted-waitcnt barrier: wait until <=K LDS ops outstanding, then s_barrier.
// DS ops retire in-order, so writes issued BEFORE the last K reads are complete.
__device__ __forceinline__ void bar_k(int K) {
    switch (K) {
    case 0: asm volatile("s_waitcnt lgkmcnt(0)" ::: "memory"); break;
    case 1: asm volatile("s_waitcnt lgkmcnt(1)" ::: "memory"); break;
    case 2: asm volatile("s_waitcnt lgkmcnt(2)" ::: "memory"); break;
    case 3: asm volatile("s_waitcnt lgkmcnt(3)" ::: "memory"); break;
    case 4: asm volatile("s_waitcnt lgkmcnt(4)" ::: "memory"); break;
    case 5: asm volatile("s_waitcnt lgkmcnt(5)" ::: "memory"); break;
    case 6: asm volatile("s_waitcnt lgkmcnt(6)" ::: "memory"); break;
    default: asm volatile("s_waitcnt lgkmcnt(7)" ::: "memory"); break;
    }
    __builtin_amdgcn_s_barrier();
}

// 4-lane max reduction via DPP quad_perm (VALU pipe, not DS pipe).
__device__ __forceinline__ float qmax1(float v) {   // xor 1: perm {1,0,3,2}
    int t = __builtin_amdgcn_update_dpp(0, __float_as_int(v), 0xB1, 0xF, 0xF, true);
    return fmaxf(v, __int_as_float(t));
}
__device__ __forceinline__ float qmax2(float v) {   // xor 2: perm {2,3,0,1}
    int t = __builtin_amdgcn_update_dpp(0, __float_as_int(v), 0x4E, 0xF, 0xF, true);
    return fmaxf(v, __int_as_float(t));
}

// ---------------------------------------------------------------------------
// Kernel 1 (v5): pot + gold partials + inline len + out zeroing.
// ---------------------------------------------------------------------------
__global__ __launch_bounds__(256) void pot_gold_kernel(
    const float* __restrict__ logits, const int* __restrict__ labels,
    float* __restrict__ pot, float* __restrict__ gpart, float* __restrict__ out)
{
    const int tid = threadIdx.x;
    const int wave = tid >> 6, lane = tid & 63;
    __shared__ __align__(16) float LP[4 * 16 * 36];   // 9216 B
    __shared__ float gred[4];
    __shared__ int s_len;
    float* W = LP + wave * (16 * 36);

    const int block_cell0 = blockIdx.x * 256;
    const int b = block_cell0 >> 14;
    const bool has_row0 = (blockIdx.x & 63) == 0;

    if (blockIdx.x == 0 && tid == 0) out[0] = 0.0f;   // replaces hipMemsetAsync

    if (has_row0 && tid < 64) {
        const size_t base = (size_t)b << 14;
        int cnt = (labels[base + tid] != -100) + (labels[base + 64 + tid] != -100);
        #pragma unroll
        for (int d = 32; d; d >>= 1) cnt += __shfl_down(cnt, d, 64);
        if (tid == 0) s_len = cnt;
    }
    __syncthreads();
    const int len = has_row0 ? s_len : -1;

    float gacc = 0.0f;
    const int wave_cell0 = block_cell0 + wave * 64;

    #pragma unroll
    for (int chunk = 0; chunk < 4; ++chunk) {
        const int c0 = wave_cell0 + chunk * 16;
        const float4* src = reinterpret_cast<const float4*>(logits) + ((size_t)c0 << 3);
        const float4 f0 = src[lane];
        const float4 f1 = src[lane + 64];
        const int lv = (lane < 16) ? labels[c0 + lane] : 0;

        {
            const int cA = lane >> 3, tA = lane & 7;
            *reinterpret_cast<float4*>(W + cA * 36 + tA * 4) = f0;
            const int q1 = lane + 64;
            const int cB = q1 >> 3, tB = q1 & 7;
            *reinterpret_cast<float4*>(W + cB * 36 + tB * 4) = f1;
        }
        const int c = lane >> 2, u = lane & 3;
        const float4 r0 = *reinterpret_cast<const float4*>(W + c * 36 + u * 8);
        const float4 r1 = *reinterpret_cast<const float4*>(W + c * 36 + u * 8 + 4);

        int lab = __shfl(lv, c, 64);
        if (lab < 0) lab = 0;
        const float l0 = __shfl(r0.x, c << 2, 64);

        const int cell = c0 + c;
        const int ci = (cell >> 7) & (SEQ - 1);
        const int cj = cell & (SEQ - 1);
        const bool special = (ci == 0) && (cj == len - 1);

        const float vv[8] = { r0.x, r0.y, r0.z, r0.w, r1.x, r1.y, r1.z, r1.w };
        float m = NEGF, g = 0.0f;
        #pragma unroll
        for (int e = 0; e < 8; ++e) {
            const int l = u * 8 + e;
            const float r = vv[e] - l0;
            const bool isg = (l == lab);
            g = isg ? r : g;
            float cand = r + (isg ? 0.0f : 1.0f);
            if (l == 0 && special) cand -= 1.0e9f;
            m = fmaxf(m, cand);
        }
        m = fmaxf(m, __shfl_xor(m, 1, 64));
        m = fmaxf(m, __shfl_xor(m, 2, 64));
        g += __shfl_xor(g, 1, 64);
        g += __shfl_xor(g, 2, 64);
        if (u == 0) {
            pot[cell] = m;
            gacc += g;
        }
    }

    #pragma unroll
    for (int d = 1; d < 64; d <<= 1) gacc += __shfl_xor(gacc, d, 64);
    if (lane == 0) gred[wave] = gacc;
    __syncthreads();
    if (tid == 0)
        gpart[blockIdx.x] = gred[0] + gred[1] + gred[2] + gred[3];
}

// ---------------------------------------------------------------------------
// Kernel 2 (v10): chunked two-phase CKY, DS-throughput-optimized phase B.
// Edge-term loads split across the 4 s-lanes of each row (lane s owns
// m in [4s,4s+4)); per step the wave issues only:
//   1 uniform "fresh" quad read (contains the value written last step),
//   1 bo-prefetch quad, 1 bf-prefetch quad (for next step, in flight across
//   the counted barrier), 1 fused A/Bt write (per-lane address select).
// Partial maxes combined across s via DPP quad_perm (VALU, not DS pipe).
// All register-array indices compile-time (d-loops fully unrolled).
// ---------------------------------------------------------------------------
__global__ __launch_bounds__(512, 1) void cky_kernel(
    const float* __restrict__ pot, const float* __restrict__ gpart,
    const int* __restrict__ labels, float* __restrict__ out)
{
    const int b = blockIdx.x;
    const int tid = threadIdx.x;
    const float* p = pot + (size_t)b * SEQ * SEQ;

    __shared__ __align__(16) float A[SEQ * PA];       // 67584 B
    __shared__ __align__(16) float Bt[SEQ * PA];      // 67584 B
    __shared__ int s_len;
    __shared__ float s_gold;

    if (tid < 64) {                                   // len[b]
        const size_t base = (size_t)b << 14;
        int cnt = (labels[base + tid] != -100) + (labels[base + 64 + tid] != -100);
        #pragma unroll
        for (int d = 32; d; d >>= 1) cnt += __shfl_down(cnt, d, 64);
        if (tid == 0) s_len = cnt;
    } else if (tid < 128) {                           // gold[b] from partials
        float g = gpart[b * 64 + (tid - 64)];
        #pragma unroll
        for (int d = 32; d; d >>= 1) g += __shfl_down(g, d, 64);
        if (tid == 64) s_gold = g;
    }

    {   // scatter pot into both tables; preload all 8 quads first (ILP)
        const float4* p4 = reinterpret_cast<const float4*>(p);
        float4 vb[8];
        #pragma unroll
        for (int t = 0; t < 8; ++t) vb[t] = p4[tid + 512 * t];
        #pragma unroll
        for (int t = 0; t < 8; ++t) {
            const int qi = tid + 512 * t;
            const int i0 = qi >> 5;
            const int j0 = (qi & 31) << 2;
            const float vv[4] = { vb[t].x, vb[t].y, vb[t].z, vb[t].w };
            #pragma unroll
            for (int c2 = 0; c2 < 4; ++c2) {
                const int j = j0 + c2;
                if (j >= i0) {
                    A[i0 * PA + (j - i0)] = vv[c2];
                    Bt[j * PA + (SEQ - 1 - (j - i0))] = vv[c2];
                }
            }
        }
    }
    __syncthreads();

    const int i = tid >> 2, s = tid & 3;
    float alo[16], av[16], pv[16], md[16];
    float boq[4], bfq[4];

    // lane-s edge body, chunk 0 (bo terms only; lane SS uses the fresh quad)
#define C0_BODY(Sv)                                                           \
    if (s == (Sv)) {                                                          \
        _Pragma("unroll")                                                     \
        for (int e = 0; e < 4; ++e) {                                         \
            const int m = 4 * (Sv) + e;                                       \
            if (m < d) {                                                      \
                const float bv = ((Sv) == ((d - 1) >> 2))                     \
                    ? ((e == 0) ? fq.w : (e == 1) ? fq.z : (e == 2) ? fq.y : fq.x) \
                    : boq[e];                                                 \
                part = fmaxf(part, av[d - 1 - m] + bv);                       \
            }                                                                 \
        }                                                                     \
    }

    // lane-s edge body, chunks >= 16 (bo via prefetch, bf fresh-or-prefetch)
#define CH_BODY(Sv)                                                           \
    if (s == (Sv)) {                                                          \
        _Pragma("unroll")                                                     \
        for (int e = 0; e < 4; ++e) {                                         \
            const int m = 4 * (Sv) + e;                                       \
            if (m < d) {                                                      \
                part = fmaxf(part, av[d - 1 - m] + boq[e]);                   \
                const float bv = ((Sv) == ((d - 1) >> 2))                     \
                    ? ((e == 0) ? fq.w : (e == 1) ? fq.z : (e == 2) ? fq.y : fq.x) \
                    : bfq[e];                                                 \
                part = fmaxf(part, alo[d - 1 - m] + bv);                      \
            }                                                                 \
        }                                                                     \
    }

    // ---------------- chunk 0: w = 1..15 ----------------
    #pragma unroll
    for (int t = 0; t < 4; ++t) {
        const float4 v = *reinterpret_cast<const float4*>(&A[i * PA + 4 * t]);
        pv[4*t] = v.x; pv[4*t+1] = v.y; pv[4*t+2] = v.z; pv[4*t+3] = v.w;
    }
    av[0] = pv[0];

    {   // initial prefetch for step d=1 (row i+1, quad t=s, widths 4s..4s+3)
        const int jp = (i + 1 < SEQ) ? (i + 1) : (SEQ - 1);
        const float4 bv = *reinterpret_cast<const float4*>(&Bt[jp * PA + 124 - 4 * s]);
        boq[0] = bv.w; boq[1] = bv.z; boq[2] = bv.y; boq[3] = bv.x;
    }

    #pragma unroll
    for (int d = 1; d < 16; ++d) {
        const int j = i + d;
        const int jr = (j < SEQ) ? j : SEQ - 1;
        // uniform fresh quad: t = (d-1)>>2 of row j (contains width d-1)
        const float4 fq = *reinterpret_cast<const float4*>(&Bt[jr * PA + 124 - 4 * ((d - 1) >> 2)]);
        float part = NEGF;
        C0_BODY(0)
        C0_BODY(1)
        C0_BODY(2)
        C0_BODY(3)
        part = qmax2(qmax1(part));
        const float val = part + pv[d];
        av[d] = val;
        if (j < SEQ && s < 2) {
            float* pw = (s == 0) ? &A[i * PA + d] : &Bt[j * PA + (SEQ - 1 - d)];
            *pw = val;
        }
        __builtin_amdgcn_sched_barrier(0);
        if (d < 15) {   // prefetch own quad t=s of row j+1 for step d+1
            const int jp = (j + 1 < SEQ) ? (j + 1) : (SEQ - 1);
            const float4 bv = *reinterpret_cast<const float4*>(&Bt[jp * PA + 124 - 4 * s]);
            boq[0] = bv.w; boq[1] = bv.z; boq[2] = bv.y; boq[3] = bv.x;
            bar_k(1);
        } else {
            bar_k(0);
        }
    }
    #pragma unroll
    for (int k = 0; k < 16; ++k) alo[k] = av[k];

    // ---------------- chunks W = 16..112 ----------------
    for (int W = 16; W < SEQ; W += 16) {
        // pv = A[i][W..W+15] (pot values, stable until this chunk's writes)
        #pragma unroll
        for (int t = 0; t < 4; ++t) {
            const float4 v = *reinterpret_cast<const float4*>(&A[i * PA + W + 4 * t]);
            pv[4*t] = v.x; pv[4*t+1] = v.y; pv[4*t+2] = v.z; pv[4*t+3] = v.w;
        }
        #pragma unroll
        for (int d = 0; d < 16; ++d) md[d] = NEGF;

        // ---- phase A: bulk k in [d, W-1], all data pre-chunk ----
        {   // first quad (k0 = 4s <= 12): mask k >= d
            const int k0 = s << 2;
            const float4 a = *reinterpret_cast<const float4*>(&A[i * PA + k0]);
            const float aa[4] = { a.x, a.y, a.z, a.w };
            #pragma unroll
            for (int d = 0; d < 16; ++d) {
                const int j = i + W + d;
                if (j < SEQ) {
                    const float* bp = &Bt[j * PA + (SEQ - W - d) + k0];
                    float b0, b1, b2, b3;
                    if ((d & 3) == 0) {
                        const float4 v = *reinterpret_cast<const float4*>(bp);
                        b0 = v.x; b1 = v.y; b2 = v.z; b3 = v.w;
                    } else if ((d & 3) == 2) {
                        const float2 v0 = *reinterpret_cast<const float2*>(bp);
                        const float2 v1 = *reinterpret_cast<const float2*>(bp + 2);
                        b0 = v0.x; b1 = v0.y; b2 = v1.x; b3 = v1.y;
                    } else {
                        b0 = bp[0];
                        const float2 v = *reinterpret_cast<const float2*>(bp + 1);
                        b1 = v.x; b2 = v.y; b3 = bp[3];
                    }
                    const float a0 = (k0 + 0 >= d) ? aa[0] : NEGF;
                    const float a1 = (k0 + 1 >= d) ? aa[1] : NEGF;
                    const float a2 = (k0 + 2 >= d) ? aa[2] : NEGF;
                    const float a3 = (k0 + 3 >= d) ? aa[3] : NEGF;
                    md[d] = fmaxf(md[d], fmaxf(fmaxf(a0 + b0, a1 + b1),
                                               fmaxf(a2 + b2, a3 + b3)));
                }
            }
        }
        for (int q = s + 4; q < (W >> 2); q += 4) {   // k0 >= 16 > d: no masks
            const int k0 = q << 2;
            const float4 a = *reinterpret_cast<const float4*>(&A[i * PA + k0]);
            #pragma unroll
            for (int d = 0; d < 16; ++d) {
                const int j = i + W + d;
                if (j < SEQ) {
                    const float* bp = &Bt[j * PA + (SEQ - W - d) + k0];
                    float b0, b1, b2, b3;
                    if ((d & 3) == 0) {
                        const float4 v = *reinterpret_cast<const float4*>(bp);
                        b0 = v.x; b1 = v.y; b2 = v.z; b3 = v.w;
                    } else if ((d & 3) == 2) {
                        const float2 v0 = *reinterpret_cast<const float2*>(bp);
                        const float2 v1 = *reinterpret_cast<const float2*>(bp + 2);
                        b0 = v0.x; b1 = v0.y; b2 = v1.x; b3 = v1.y;
                    } else {
                        b0 = bp[0];
                        const float2 v = *reinterpret_cast<const float2*>(bp + 1);
                        b1 = v.x; b2 = v.y; b3 = bp[3];
                    }
                    md[d] = fmaxf(md[d], fmaxf(fmaxf(a.x + b0, a.y + b1),
                                               fmaxf(a.z + b2, a.w + b3)));
                }
            }
        }
        #pragma unroll
        for (int d = 0; d < 16; ++d) {    // 4-lane butterfly via DPP (VALU)
            md[d] = qmax2(qmax1(md[d]));
        }

        // ---- phase B ----
        {   // step d = 0: no edge terms; prefetch both quads for step 1
            const int j = i + W;
            const float val = md[0] + pv[0];
            av[0] = val;
            if (j < SEQ && s < 2) {
                float* pw = (s == 0) ? &A[i * PA + W] : &Bt[j * PA + (SEQ - 1 - W)];
                *pw = val;
            }
            __builtin_amdgcn_sched_barrier(0);
            const int jp = (j + 1 < SEQ) ? (j + 1) : (SEQ - 1);
            const float4 bv = *reinterpret_cast<const float4*>(&Bt[jp * PA + 124 - 4 * s]);
            const float4 fv = *reinterpret_cast<const float4*>(&Bt[jp * PA + 124 - W - 4 * s]);
            boq[0] = bv.w; boq[1] = bv.z; boq[2] = bv.y; boq[3] = bv.x;
            bfq[0] = fv.w; bfq[1] = fv.z; bfq[2] = fv.y; bfq[3] = fv.x;
            bar_k(2);
        }
        #pragma unroll
        for (int d = 1; d < 16; ++d) {
            const int w = W + d;
            const int j = i + w;
            const int jr = (j < SEQ) ? j : SEQ - 1;
            // uniform fresh bf quad: t=(d-1)>>2 of row j (contains width w-1)
            const float4 fq = *reinterpret_cast<const float4*>(
                &Bt[jr * PA + 124 - W - 4 * ((d - 1) >> 2)]);
            float part = NEGF;
            CH_BODY(0)
            CH_BODY(1)
            CH_BODY(2)
            CH_BODY(3)
            part = qmax2(qmax1(part));
            const float val = fmaxf(part, md[d]) + pv[d];
            av[d] = val;
            if (j < SEQ && s < 2) {
                float* pw = (s == 0) ? &A[i * PA + w] : &Bt[j * PA + (SEQ - 1 - w)];
                *pw = val;
            }
            __builtin_amdgcn_sched_barrier(0);
            if (d < 15) {   // prefetch own bo+bf quads of row j+1 for step d+1
                const int jp = (j + 1 < SEQ) ? (j + 1) : (SEQ - 1);
                const float4 bv = *reinterpret_cast<const float4*>(&Bt[jp * PA + 124 - 4 * s]);
                const float4 fv = *reinterpret_cast<const float4*>(&Bt[jp * PA + 124 - W - 4 * s]);
                boq[0] = bv.w; boq[1] = bv.z; boq[2] = bv.y; boq[3] = bv.x;
                bfq[0] = fv.w; bfq[1] = fv.z; bfq[2] = fv.y; bfq[3] = fv.x;
                bar_k(2);
            } else {
                bar_k(0);
            }
        }
    }

    if (tid == 0) {
        const int len = s_len;
        const float pred = A[len - 1];        // A[0][len-1]
        const float margin = fmaxf(pred - s_gold, 0.0f);
        atomicAdd(out, margin * (1.0f / (float)BATCH));
    }
#undef C0_BODY
#undef CH_BODY
}

extern "C" void kernel_launch(void* const* d_in, const int* in_sizes, int n_in,
                              void* d_out, int out_size, void* d_ws, size_t ws_size,
                              hipStream_t stream) {
    const float* logits = (const float*)d_in[0];
    const int* labels = (const int*)d_in[1];
    float* out = (float*)d_out;

    float* pot = (float*)d_ws;                          // B*N*N floats = 4 MB
    float* gpart = pot + (size_t)BATCH * SEQ * SEQ;     // 4096 floats

    pot_gold_kernel<<<BATCH * SEQ * SEQ / 256, 256, 0, stream>>>(
        logits, labels, pot, gpart, out);
    cky_kernel<<<BATCH, 512, 0, stream>>>(pot, gpart, labels, out);
}